// Round 9
// baseline (849.737 us; speedup 1.0000x reference)
//
#include <hip/hip_runtime.h>

#define NV 8192
#define NC 128
#define VP 64
#define FP 124
#define NBLK 128
#define NTHR 256
#define MAXSLOT 26   // bbox half-extent <= 0.5, spacing 0.8 -> <=26 neighbors
#define NSL 7        // max slots per wave = ceil(26/4)

typedef unsigned long long ull;

// Coherent (MALL-level) accessors: global_load/store with sc1, bypassing the
// non-coherent per-XCD L2.
__device__ __forceinline__ float ald(const float* p) {
  return __hip_atomic_load(p, __ATOMIC_RELAXED, __HIP_MEMORY_SCOPE_AGENT);
}
__device__ __forceinline__ int aldi(const int* p) {
  return __hip_atomic_load(p, __ATOMIC_RELAXED, __HIP_MEMORY_SCOPE_AGENT);
}
__device__ __forceinline__ void ast(float* p, float v) {
  __hip_atomic_store(p, v, __ATOMIC_RELAXED, __HIP_MEMORY_SCOPE_AGENT);
}
__device__ __forceinline__ void asti(int* p, int v) {
  __hip_atomic_store(p, v, __ATOMIC_RELAXED, __HIP_MEMORY_SCOPE_AGENT);
}

// Vertex reconstruction from group-mean sums (identical expression everywhere
// so all blocks compute bitwise-identical coordinates).
__device__ __forceinline__ void recon3(const float* ps1, const float* ps2,
                                       const float* pc, int l,
                                       float& x, float& y, float& z) {
  float cc = fmaxf(ald(&pc[l]), 1.f);
  x = ald(&ps1[3*l+0])/cc + 1e-5f*(ald(&ps2[3*l+0])/cc);
  y = ald(&ps1[3*l+1])/cc + 1e-5f*(ald(&ps2[3*l+1])/cc);
  z = ald(&ps1[3*l+2])/cc + 1e-5f*(ald(&ps2[3*l+2])/cc);
}

// ---- global lock-free union-find (ECL-CC style, min-root) ----
// Invariant: parent[x] <= x, monotone decreasing -> acyclic, terminates.
__device__ __forceinline__ int findc(int* parent, int x) {
  int p = aldi(&parent[x]);
  if (p == x) return x;
  for (;;) {
    int gp = aldi(&parent[p]);
    if (gp == p) return p;
    atomicMin(&parent[x], gp);   // path halving (monotone-safe)
    x = p; p = gp;
  }
}
__device__ __forceinline__ void ghook(int* parent, int i, int j) {
  int a = i, b = j;
  for (;;) {
    a = findc(parent, a);
    b = findc(parent, b);
    if (a == b) return;
    int hi = a > b ? a : b, lo = a > b ? b : a;
    int old = atomicMin(&parent[hi], lo);
    if (old == hi) return;       // hi was a root, now hooked under lo
    a = old; b = lo;             // retry with hi's previous parent
  }
}
// ---- block-local LDS union-find over own 64 verts ----
__device__ __forceinline__ void lhook(volatile int* lp, int a, int b) {
  for (;;) {
    while (lp[a] != a) a = lp[a];
    while (lp[b] != b) b = lp[b];
    if (a == b) return;
    int hi = a > b ? a : b, lo = a > b ? b : a;
    int old = atomicMin((int*)&lp[hi], lo);
    if (old == hi) return;
    a = old; b = lo;
  }
}

// Simple monotone-counter barrier (round-5 design, best measured).
__device__ __forceinline__ void gbar(int* syncv, int seq, int t) {
  asm volatile("s_waitcnt vmcnt(0)" ::: "memory");
  __syncthreads();
  if (t == 0) {
    int old = __hip_atomic_fetch_add(&syncv[0], 1, __ATOMIC_RELAXED, __HIP_MEMORY_SCOPE_AGENT);
    if (old == seq * NBLK - 1)
      __hip_atomic_store(&syncv[32], seq, __ATOMIC_RELAXED, __HIP_MEMORY_SCOPE_AGENT);
    else
      while (__hip_atomic_load(&syncv[32], __ATOMIC_RELAXED, __HIP_MEMORY_SCOPE_AGENT) < seq)
        __builtin_amdgcn_s_sleep(1);
  }
  __syncthreads();
}

__global__ __launch_bounds__(NTHR, 1)
void soap_fused(const float* __restrict__ inV, const float* __restrict__ bb,
                const float* __restrict__ pP, const float* __restrict__ pS,
                const int* __restrict__ faces, const int* __restrict__ cfl,
                float* __restrict__ out, int* __restrict__ parent,
                int* __restrict__ labelsF,
                float* __restrict__ sumsA, float* __restrict__ countsA,
                float* __restrict__ sumsB, int* syncv) {
  const float T2 = (float)(0.3 * 0.3);
  const int c = blockIdx.x;
  const int t = threadIdx.x;
  const int q = t >> 6;   // wave id 0..3
  const int v = t & 63;   // lane id

  __shared__ float s_vx[VP], s_vy[VP], s_vz[VP], s_sq[VP];
  __shared__ float s_gx[VP], s_gy[VP], s_gz[VP];
  __shared__ float s_fx[VP], s_fy[VP], s_fz[VP];
  __shared__ int   s_lab[VP], s_lp[VP];
  __shared__ int   s_hcell[MAXSLOT];
  __shared__ int   s_KH;
  __shared__ ull   s_adjw[2];
  __shared__ float s_cx, s_cy, s_cz, s_vol, s_csx, s_csy, s_csz;

  int seq = 0;

  // ---- adjacency from bboxes; keep only neighbors with id > c ----
  if (q < 2) {
    int b = q * 64 + v;
    float anx = bb[c*6+0], any_ = bb[c*6+1], anz = bb[c*6+2];
    float axx = bb[c*6+3], axy = bb[c*6+4], axz = bb[c*6+5];
    float bnx = bb[b*6+0], bny = bb[b*6+1], bnz = bb[b*6+2];
    float bxx = bb[b*6+3], bxy = bb[b*6+4], bxz = bb[b*6+5];
    bool ov = (b > c) && (anx <= bxx) && (any_ <= bxy) && (anz <= bxz) &&
              (bnx <= axx) && (bny <= axy) && (bnz <= axz);
    ull w = __ballot(ov);
    if (v == 0) s_adjw[q] = w;
  }
  __syncthreads();
  if (t == 0) {
    int slot = 0;
    for (int wd = 0; wd < 2; ++wd) {
      ull aw = s_adjw[wd];
      while (aw) {
        int bbit = __ffsll((long long)aw) - 1; aw &= aw - 1;
        if (slot < MAXSLOT) s_hcell[slot] = wd * 64 + bbit;
        ++slot;
      }
    }
    s_KH = slot;
  }
  __syncthreads();
  const int KH = s_KH;

  // ---- prologue: zero both parities + init parent ----
  for (int pr = 0; pr < 2; ++pr) {
    for (int idx = t; idx < VP*3; idx += NTHR) {
      ast(&sumsA[pr*NV*3 + c*VP*3 + idx], 0.f);
      ast(&sumsB[pr*NV*3 + c*VP*3 + idx], 0.f);
    }
    if (t < VP) ast(&countsA[pr*NV + c*VP + t], 0.f);
  }
  if (t < VP) asti(&parent[c*VP + t], c*VP + t);
  gbar(syncv, ++seq, t);

  for (int it = 0; it < 5; ++it) {
    const int p = it & 1;
    float* cs1 = sumsA + p*(NV*3);
    float* cc1 = countsA + p*NV;
    float* cs2 = sumsB + p*(NV*3);
    float* ps1 = sumsA + (p^1)*(NV*3);
    float* pc  = countsA + (p^1)*NV;
    float* ps2 = sumsB + (p^1)*(NV*3);

    // ===== PHASE 1+2: stage own verts, local lp init, hook contacts =====
    if (t < VP) {
      int i = c*VP + t;
      float x, y, z;
      if (it == 0) { x = inV[3*i+0]; y = inV[3*i+1]; z = inV[3*i+2]; }
      else         { recon3(ps1, ps2, pc, s_lab[t], x, y, z); }
      s_vx[t] = x; s_vy[t] = y; s_vz[t] = z; s_sq[t] = x*x + y*y + z*z;
      s_lp[t] = t;
    }
    __syncthreads();
    {
      float xs[NSL], ys[NSL], zs[NSL];
      int   jb[NSL];
#pragma unroll
      for (int s = 0; s < NSL; ++s) { int slot = q + 4*s; if (slot < KH) {
        int bcell = s_hcell[slot];
        jb[s] = bcell*VP;
        if (it == 0) {
          int j = bcell*VP + v;
          xs[s] = inV[3*j+0]; ys[s] = inV[3*j+1]; zs[s] = inV[3*j+2];
        } else {
          int lF = aldi(&labelsF[bcell*VP + v]);
          recon3(ps1, ps2, pc, lF, xs[s], ys[s], zs[s]);
        }
      } }
#pragma unroll
      for (int s = 0; s < NSL; ++s) { int slot = q + 4*s; if (slot < KH) {
        float X = xs[s], Y = ys[s], Z = zs[s];
        float sqj = X*X + Y*Y + Z*Z;
        ull myw = 0;
        for (int vv = 0; vv < VP; ++vv) {
          float d2 = s_sq[vv] + sqj - 2.f*(s_vx[vv]*X + s_vy[vv]*Y + s_vz[vv]*Z);
          if (d2 < T2) myw |= (1ull << vv);
        }
        if (myw) {
          int first = __ffsll((long long)myw) - 1;
          ghook(parent, c*VP + first, jb[s] + v);   // one global hook per lane/slot
          ull m = myw & (myw - 1);
          int prev = first;
          while (m) {   // chain own-side contacts through block-local UF
            int nb = __ffsll((long long)m) - 1; m &= m - 1;
            lhook(s_lp, prev, nb);
            prev = nb;
          }
        }
      } }
    }
    __syncthreads();
    if (t < VP) {   // merge local trees into global UF
      int r = t;
      while (s_lp[r] != r) r = s_lp[r];
      if (r != t) ghook(parent, c*VP + t, c*VP + r);
    }
    gbar(syncv, ++seq, t);   // B: all hooks complete

    // ===== PHASE 3: find labels + publish + zero prev parity + scatter =====
    if (t < VP) {
      int l = findc(parent, c*VP + t);   // = component min = converged labels
      s_lab[t] = l;
      asti(&labelsF[c*VP + t], l);
    }
    for (int idx = t; idx < VP*3; idx += NTHR) {
      ast(&ps1[c*VP*3 + idx], 0.f);      // prev parity dead after phase 2
      ast(&ps2[c*VP*3 + idx], 0.f);
    }
    if (t < VP) ast(&pc[c*VP + t], 0.f);
    __syncthreads();
    if (t < VP) {
      int l = s_lab[t];
      bool leader = true;
      for (int s = 0; s < t; ++s) if (s_lab[s] == l) { leader = false; break; }
      if (leader) {
        float sx = 0.f, sy = 0.f, sz = 0.f, cn = 0.f;
        for (int s = t; s < VP; ++s)
          if (s_lab[s] == l) { sx += s_vx[s]; sy += s_vy[s]; sz += s_vz[s]; cn += 1.f; }
        atomicAdd(&cs1[3*l+0], sx);
        atomicAdd(&cs1[3*l+1], sy);
        atomicAdd(&cs1[3*l+2], sz);
        atomicAdd(&cc1[l], cn);
      }
    }
    gbar(syncv, ++seq, t);   // C: vert sums complete

    // ===== PHASE 4: gather + cell forces + scatter(forces) + parent reinit ==
    if (t < VP) {
      int l = s_lab[t];
      float cc = fmaxf(ald(&cc1[l]), 1.f);
      s_vx[t] = ald(&cs1[3*l+0]) / cc;
      s_vy[t] = ald(&cs1[3*l+1]) / cc;
      s_vz[t] = ald(&cs1[3*l+2]) / cc;
      s_gx[t] = 0.f; s_gy[t] = 0.f; s_gz[t] = 0.f;
    }
    if (t == 0) { s_vol = 0.f; s_csx = 0.f; s_csy = 0.f; s_csz = 0.f; }
    __syncthreads();
    if (t < VP) {
      float sx = s_vx[t], sy = s_vy[t], sz = s_vz[t];
#pragma unroll
      for (int o = 32; o; o >>= 1) { sx += __shfl_xor(sx, o); sy += __shfl_xor(sy, o); sz += __shfl_xor(sz, o); }
      if (t == 0) { s_cx = sx*(1.f/VP); s_cy = sy*(1.f/VP); s_cz = sz*(1.f/VP); }
    }
    __syncthreads();
    {
      float cx = s_cx, cy = s_cy, cz = s_cz;
      bool act = (t < FP);
      int ia = 0, ib = 0, ic = 0;
      float p0x=0,p0y=0,p0z=0,p1x=0,p1y=0,p1z=0,p2x=0,p2y=0,p2z=0;
      float q0x=0,q0y=0,q0z=0;
      if (act) {
        int f = cfl[c*FP + t];
        ia = faces[3*f+0] - c*VP; ib = faces[3*f+1] - c*VP; ic = faces[3*f+2] - c*VP;
        p0x = s_vx[ia]-cx; p0y = s_vy[ia]-cy; p0z = s_vz[ia]-cz;
        p1x = s_vx[ib]-cx; p1y = s_vy[ib]-cy; p1z = s_vz[ib]-cz;
        p2x = s_vx[ic]-cx; p2y = s_vy[ic]-cy; p2z = s_vz[ic]-cz;
        q0x = p1y*p2z - p1z*p2y;
        q0y = p1z*p2x - p1x*p2z;
        q0z = p1x*p2y - p1y*p2x;
        float term = p0x*q0x + p0y*q0y + p0z*q0z;
        atomicAdd(&s_vol, term);
      }
      __syncthreads();
      float press = pP[0]*190.f + 10.f;
      float st    = pS[0]*0.018f + 0.002f;
      float tv    = expf(press / 2500.f);
      float vol   = s_vol / 6.f;
      float coeff = 2500.f * (vol - tv);
      if (act) {
        float q1x = p2y*p0z - p2z*p0y;
        float q1y = p2z*p0x - p2x*p0z;
        float q1z = p2x*p0y - p2y*p0x;
        float q2x = p0y*p1z - p0z*p1y;
        float q2y = p0z*p1x - p0x*p1z;
        float q2z = p0x*p1y - p0y*p1x;
        float e1x = p1x-p0x, e1y = p1y-p0y, e1z = p1z-p0z;
        float e2x = p2x-p0x, e2y = p2y-p0y, e2z = p2z-p0z;
        float nx = e1y*e2z - e1z*e2y;
        float ny = e1z*e2x - e1x*e2z;
        float nz = e1x*e2y - e1y*e2x;
        float S  = nx*nx + ny*ny + nz*nz + 1e-12f;
        float wt = st / (2.f * sqrtf(S));
        float dx = e1x-e2x, dy = e1y-e2y, dz = e1z-e2z;
        float g0x = wt*(dy*nz - dz*ny), g0y = wt*(dz*nx - dx*nz), g0z = wt*(dx*ny - dy*nx);
        float g1x = wt*(e2y*nz - e2z*ny), g1y = wt*(e2z*nx - e2x*nz), g1z = wt*(e2x*ny - e2y*nx);
        float g2x = wt*(ny*e1z - nz*e1y), g2y = wt*(nz*e1x - nx*e1z), g2z = wt*(nx*e1y - ny*e1x);
        float k = coeff / 6.f;
        atomicAdd(&s_gx[ia], g0x + k*q0x); atomicAdd(&s_gy[ia], g0y + k*q0y); atomicAdd(&s_gz[ia], g0z + k*q0z);
        atomicAdd(&s_gx[ib], g1x + k*q1x); atomicAdd(&s_gy[ib], g1y + k*q1y); atomicAdd(&s_gz[ib], g1z + k*q1z);
        atomicAdd(&s_gx[ic], g2x + k*q2x); atomicAdd(&s_gy[ic], g2y + k*q2y); atomicAdd(&s_gz[ic], g2z + k*q2z);
        atomicAdd(&s_csx, q0x+q1x+q2x);
        atomicAdd(&s_csy, q0y+q1y+q2y);
        atomicAdd(&s_csz, q0z+q1z+q2z);
      }
      __syncthreads();
      if (t < VP) {
        float corr = coeff / 384.f;   // coeff * (1/6) * (1/64) centroid chain
        s_fx[t] = -(s_gx[t] - corr*s_csx);
        s_fy[t] = -(s_gy[t] - corr*s_csy);
        s_fz[t] = -(s_gz[t] - corr*s_csz);
      }
    }
    __syncthreads();
    if (t < VP) {
      int l = s_lab[t];
      bool leader = true;
      for (int s = 0; s < t; ++s) if (s_lab[s] == l) { leader = false; break; }
      if (leader) {
        float sx = 0.f, sy = 0.f, sz = 0.f;
        for (int s = t; s < VP; ++s)
          if (s_lab[s] == l) { sx += s_fx[s]; sy += s_fy[s]; sz += s_fz[s]; }
        atomicAdd(&cs2[3*l+0], sx);
        atomicAdd(&cs2[3*l+1], sy);
        atomicAdd(&cs2[3*l+2], sz);
      }
    }
    if (t < VP) asti(&parent[c*VP + t], c*VP + t);   // reinit for next iter
    gbar(syncv, ++seq, t);   // D: force sums + parent reinit complete

    // ===== it==4: write final vertices straight to d_out ================
    if (it == 4 && t < VP) {
      int i = c*VP + t;
      int l = s_lab[t];
      float cc = fmaxf(ald(&cc1[l]), 1.f);
      out[3*i+0] = s_vx[t] + 1e-5f*(ald(&cs2[3*l+0])/cc);
      out[3*i+1] = s_vy[t] + 1e-5f*(ald(&cs2[3*l+1])/cc);
      out[3*i+2] = s_vz[t] + 1e-5f*(ald(&cs2[3*l+2])/cc);
    }
  }
}

extern "C" void kernel_launch(void* const* d_in, const int* in_sizes, int n_in,
                              void* d_out, int out_size, void* d_ws, size_t ws_size,
                              hipStream_t stream) {
  const float* inV   = (const float*)d_in[0];
  const float* bb    = (const float*)d_in[1];
  const float* pP    = (const float*)d_in[2];
  const float* pS    = (const float*)d_in[3];
  const int*   faces = (const int*)d_in[4];
  const int*   cfl   = (const int*)d_in[6];

  char* w = (char*)d_ws;
  int*   parent  = (int*)w;   w += NV*sizeof(int);          // 32 KB
  int*   labelsF = (int*)w;   w += NV*sizeof(int);          // 32 KB
  float* sumsA   = (float*)w; w += 2*NV*3*sizeof(float);    // 192 KB (2 parities)
  float* countsA = (float*)w; w += 2*NV*sizeof(float);      // 64 KB
  float* sumsB   = (float*)w; w += 2*NV*3*sizeof(float);    // 192 KB
  int*   syncv   = (int*)w;   w += 256*sizeof(int);

  hipMemsetAsync(syncv, 0, 256*sizeof(int), stream);
  soap_fused<<<NBLK, NTHR, 0, stream>>>(inV, bb, pP, pS, faces, cfl,
                                        (float*)d_out, parent, labelsF,
                                        sumsA, countsA, sumsB, syncv);
}

// Round 10
// 668.575 us; speedup vs baseline: 1.2710x; 1.2710x over previous
//
#include <hip/hip_runtime.h>

#define NV 8192
#define NC 128
#define VP 64
#define FP 124
#define NBLK 128
#define NTHR 256
#define MAXSLOT 26   // bbox half-extent <= 0.5, spacing 0.8 -> <=26 neighbors
#define NSL 7        // max slots per wave = ceil(26/4)

typedef unsigned long long ull;

// Coherent (MALL-level) accessors: global_load/store with sc1, bypassing the
// non-coherent per-XCD L2.
__device__ __forceinline__ float ald(const float* p) {
  return __hip_atomic_load(p, __ATOMIC_RELAXED, __HIP_MEMORY_SCOPE_AGENT);
}
__device__ __forceinline__ int aldi(const int* p) {
  return __hip_atomic_load(p, __ATOMIC_RELAXED, __HIP_MEMORY_SCOPE_AGENT);
}
__device__ __forceinline__ void ast(float* p, float v) {
  __hip_atomic_store(p, v, __ATOMIC_RELAXED, __HIP_MEMORY_SCOPE_AGENT);
}
__device__ __forceinline__ void asti(int* p, int v) {
  __hip_atomic_store(p, v, __ATOMIC_RELAXED, __HIP_MEMORY_SCOPE_AGENT);
}

// Vertex reconstruction from group-mean sums (identical expression everywhere
// so all blocks compute bitwise-identical coordinates).
__device__ __forceinline__ void recon3(const float* ps1, const float* ps2,
                                       const float* pc, int l,
                                       float& x, float& y, float& z) {
  float cc = fmaxf(ald(&pc[l]), 1.f);
  x = ald(&ps1[3*l+0])/cc + 1e-5f*(ald(&ps2[3*l+0])/cc);
  y = ald(&ps1[3*l+1])/cc + 1e-5f*(ald(&ps2[3*l+1])/cc);
  z = ald(&ps1[3*l+2])/cc + 1e-5f*(ald(&ps2[3*l+2])/cc);
}

// ---- global lock-free union-find: READ-ONLY find + min-hook with retry ----
// Invariant: parent[x] <= x, all writes are atomicMin of implied-connected
// pairs -> monotone, acyclic, converges to component-min roots.
__device__ __forceinline__ int findro(const int* parent, int x) {
  int p = aldi(&parent[x]);
  while (p != x) { x = p; p = aldi(&parent[x]); }
  return x;
}
__device__ __forceinline__ void ghook(int* parent, int a, int b) {
  for (;;) {
    a = findro(parent, a);
    b = findro(parent, b);
    if (a == b) return;
    int hi = a > b ? a : b, lo = a > b ? b : a;
    int old = atomicMin(&parent[hi], lo);
    if (old == hi) return;       // hi was a root, now hooked under lo
    a = old; b = lo;             // retry with hi's previous parent
  }
}

// Monotone-counter barrier (round-5 design, best measured).
__device__ __forceinline__ void gbar(int* syncv, int seq, int t) {
  asm volatile("s_waitcnt vmcnt(0)" ::: "memory");
  __syncthreads();
  if (t == 0) {
    int old = __hip_atomic_fetch_add(&syncv[0], 1, __ATOMIC_RELAXED, __HIP_MEMORY_SCOPE_AGENT);
    if (old == seq * NBLK - 1)
      __hip_atomic_store(&syncv[32], seq, __ATOMIC_RELAXED, __HIP_MEMORY_SCOPE_AGENT);
    else
      while (__hip_atomic_load(&syncv[32], __ATOMIC_RELAXED, __HIP_MEMORY_SCOPE_AGENT) < seq)
        __builtin_amdgcn_s_sleep(1);
  }
  __syncthreads();
}

__global__ __launch_bounds__(NTHR, 1)
void soap_fused(const float* __restrict__ inV, const float* __restrict__ bb,
                const float* __restrict__ pP, const float* __restrict__ pS,
                const int* __restrict__ faces, const int* __restrict__ cfl,
                float* __restrict__ out, int* __restrict__ parent,
                int* __restrict__ labelsF,
                float* __restrict__ sumsA, float* __restrict__ countsA,
                float* __restrict__ sumsB, int* syncv) {
  const float T2 = (float)(0.3 * 0.3);
  const int c = blockIdx.x;
  const int t = threadIdx.x;
  const int q = t >> 6;   // wave id 0..3
  const int v = t & 63;   // lane id

  __shared__ float s_vx[VP], s_vy[VP], s_vz[VP], s_sq[VP];
  __shared__ float s_gx[VP], s_gy[VP], s_gz[VP];
  __shared__ float s_fx[VP], s_fy[VP], s_fz[VP];
  __shared__ int   s_lab[VP], s_ll[VP];
  __shared__ int   s_hcell[MAXSLOT];
  __shared__ int   s_KH, s_cf;
  __shared__ ull   s_adjw[2];
  __shared__ float s_cx, s_cy, s_cz, s_vol, s_csx, s_csy, s_csz;

  int seq = 0;

  // ---- adjacency from bboxes; keep only neighbors with id > c ----
  if (q < 2) {
    int b = q * 64 + v;
    float anx = bb[c*6+0], any_ = bb[c*6+1], anz = bb[c*6+2];
    float axx = bb[c*6+3], axy = bb[c*6+4], axz = bb[c*6+5];
    float bnx = bb[b*6+0], bny = bb[b*6+1], bnz = bb[b*6+2];
    float bxx = bb[b*6+3], bxy = bb[b*6+4], bxz = bb[b*6+5];
    bool ov = (b > c) && (anx <= bxx) && (any_ <= bxy) && (anz <= bxz) &&
              (bnx <= axx) && (bny <= axy) && (bnz <= axz);
    ull w = __ballot(ov);
    if (v == 0) s_adjw[q] = w;
  }
  __syncthreads();
  if (t == 0) {
    int slot = 0;
    for (int wd = 0; wd < 2; ++wd) {
      ull aw = s_adjw[wd];
      while (aw) {
        int bbit = __ffsll((long long)aw) - 1; aw &= aw - 1;
        if (slot < MAXSLOT) s_hcell[slot] = wd * 64 + bbit;
        ++slot;
      }
    }
    s_KH = slot;
  }
  __syncthreads();
  const int KH = s_KH;

  // ---- prologue: zero both parities + init parent ----
  for (int pr = 0; pr < 2; ++pr) {
    for (int idx = t; idx < VP*3; idx += NTHR) {
      ast(&sumsA[pr*NV*3 + c*VP*3 + idx], 0.f);
      ast(&sumsB[pr*NV*3 + c*VP*3 + idx], 0.f);
    }
    if (t < VP) ast(&countsA[pr*NV + c*VP + t], 0.f);
  }
  if (t < VP) asti(&parent[c*VP + t], c*VP + t);
  gbar(syncv, ++seq, t);

  for (int it = 0; it < 5; ++it) {
    const int p = it & 1;
    float* cs1 = sumsA + p*(NV*3);
    float* cc1 = countsA + p*NV;
    float* cs2 = sumsB + p*(NV*3);
    float* ps1 = sumsA + (p^1)*(NV*3);
    float* pc  = countsA + (p^1)*NV;
    float* ps2 = sumsB + (p^1)*(NV*3);

    // ===== PHASE 1: stage, contact masks, clique labels, hooks ==========
    if (t < VP) {
      int i = c*VP + t;
      float x, y, z;
      if (it == 0) { x = inV[3*i+0]; y = inV[3*i+1]; z = inV[3*i+2]; }
      else         { recon3(ps1, ps2, pc, s_lab[t], x, y, z); }
      s_vx[t] = x; s_vy[t] = y; s_vz[t] = z; s_sq[t] = x*x + y*y + z*z;
      s_ll[t] = t;
    }
    if (t == 0) s_cf = 0;
    __syncthreads();

    ull msk[NSL]; int jb[NSL];
    {
      float xs[NSL], ys[NSL], zs[NSL];
#pragma unroll
      for (int s = 0; s < NSL; ++s) {
        msk[s] = 0; jb[s] = 0;
        int slot = q + 4*s;
        if (slot < KH) {
          int bcell = s_hcell[slot];
          jb[s] = bcell*VP;
          if (it == 0) {
            int j = jb[s] + v;
            xs[s] = inV[3*j+0]; ys[s] = inV[3*j+1]; zs[s] = inV[3*j+2];
          } else {
            int lF = aldi(&labelsF[jb[s] + v]);
            recon3(ps1, ps2, pc, lF, xs[s], ys[s], zs[s]);
          }
        }
      }
#pragma unroll
      for (int s = 0; s < NSL; ++s) { int slot = q + 4*s; if (slot < KH) {
        float X = xs[s], Y = ys[s], Z = zs[s];
        float sqj = X*X + Y*Y + Z*Z;
        ull w = 0;
        for (int vv = 0; vv < VP; ++vv) {
          float d2 = s_sq[vv] + sqj - 2.f*(s_vx[vv]*X + s_vy[vv]*Y + s_vz[vv]*Z);
          if (d2 < T2) w |= (1ull << vv);
        }
        msk[s] = w;
      } }
    }

    // clique min-label propagation to fixpoint (each mask = one clique).
    // At fixpoint every clique is label-uniform => labels = local comp min.
    {
      int rounds = 0;
      for (;;) {
        bool chg = false;
#pragma unroll
        for (int s = 0; s < NSL; ++s) { if (msk[s]) {
          ull m = msk[s]; int mn = VP;
          while (m) { int b = __ffsll((long long)m) - 1; m &= m - 1;
                      mn = min(mn, s_ll[b]); }
          m = msk[s];
          while (m) { int b = __ffsll((long long)m) - 1; m &= m - 1;
                      if (s_ll[b] > mn) { atomicMin(&s_ll[b], mn); chg = true; } }
        } }
        if (chg) s_cf = 1;          // racy-benign LDS flag
        __syncthreads();
        int done = (s_cf == 0);
        __syncthreads();            // all reads of s_cf complete
        if (t == 0) s_cf = 0;
        ++rounds;
        if (done || rounds >= VP) break;   // VP=64 rounds provably converges
        __syncthreads();            // reset visible before next round writes
      }
    }

    // own chaining into global UF: one hook per non-root own vert
    if (t < VP && s_ll[t] != t) ghook(parent, c*VP + t, c*VP + s_ll[t]);

    // cross hooks with per-slot same-label dedupe: lanes sharing a local
    // component hook (j, j_leader) (depth-0 chases); leader does (L, j).
#pragma unroll
    for (int s = 0; s < NSL; ++s) { int slot = q + 4*s; if (slot < KH) {
      int L   = msk[s] ? s_ll[__ffsll((long long)msk[s]) - 1] : -1;
      int myj = jb[s] + v;
      ull act = __ballot(msk[s] != 0);
      while (act) {
        int lead = __ffsll((long long)act) - 1;
        int Ll = __shfl(L, lead);
        int jl = __shfl(myj, lead);
        ull grp = __ballot(L == Ll && msk[s] != 0) & act;
        if ((grp >> v) & 1) {
          if (v == lead) ghook(parent, c*VP + Ll, myj);
          else           ghook(parent, myj, jl);
        }
        act &= ~grp;
      }
    } }
    gbar(syncv, ++seq, t);   // B: all hooks complete

    // ===== PHASE 2: find labels + publish + zero prev parity + scatter ===
    if (t < VP) {
      int l = findro(parent, c*VP + t);   // component min = converged labels
      s_lab[t] = l;
      asti(&labelsF[c*VP + t], l);
    }
    for (int idx = t; idx < VP*3; idx += NTHR) {
      ast(&ps1[c*VP*3 + idx], 0.f);       // prev parity dead after phase 1
      ast(&ps2[c*VP*3 + idx], 0.f);
    }
    if (t < VP) ast(&pc[c*VP + t], 0.f);
    __syncthreads();
    if (t < VP) {
      int l = s_lab[t];
      bool leader = true;
      for (int s = 0; s < t; ++s) if (s_lab[s] == l) { leader = false; break; }
      if (leader) {
        float sx = 0.f, sy = 0.f, sz = 0.f, cn = 0.f;
        for (int s = t; s < VP; ++s)
          if (s_lab[s] == l) { sx += s_vx[s]; sy += s_vy[s]; sz += s_vz[s]; cn += 1.f; }
        atomicAdd(&cs1[3*l+0], sx);
        atomicAdd(&cs1[3*l+1], sy);
        atomicAdd(&cs1[3*l+2], sz);
        atomicAdd(&cc1[l], cn);
      }
    }
    gbar(syncv, ++seq, t);   // C: vert sums complete

    // ===== PHASE 3: gather + cell forces + scatter(forces) + parent reinit ==
    if (t < VP) {
      int l = s_lab[t];
      float cc = fmaxf(ald(&cc1[l]), 1.f);
      s_vx[t] = ald(&cs1[3*l+0]) / cc;
      s_vy[t] = ald(&cs1[3*l+1]) / cc;
      s_vz[t] = ald(&cs1[3*l+2]) / cc;
      s_gx[t] = 0.f; s_gy[t] = 0.f; s_gz[t] = 0.f;
    }
    if (t == 0) { s_vol = 0.f; s_csx = 0.f; s_csy = 0.f; s_csz = 0.f; }
    __syncthreads();
    if (t < VP) {
      float sx = s_vx[t], sy = s_vy[t], sz = s_vz[t];
#pragma unroll
      for (int o = 32; o; o >>= 1) { sx += __shfl_xor(sx, o); sy += __shfl_xor(sy, o); sz += __shfl_xor(sz, o); }
      if (t == 0) { s_cx = sx*(1.f/VP); s_cy = sy*(1.f/VP); s_cz = sz*(1.f/VP); }
    }
    __syncthreads();
    {
      float cx = s_cx, cy = s_cy, cz = s_cz;
      bool act = (t < FP);
      int ia = 0, ib = 0, ic = 0;
      float p0x=0,p0y=0,p0z=0,p1x=0,p1y=0,p1z=0,p2x=0,p2y=0,p2z=0;
      float q0x=0,q0y=0,q0z=0;
      if (act) {
        int f = cfl[c*FP + t];
        ia = faces[3*f+0] - c*VP; ib = faces[3*f+1] - c*VP; ic = faces[3*f+2] - c*VP;
        p0x = s_vx[ia]-cx; p0y = s_vy[ia]-cy; p0z = s_vz[ia]-cz;
        p1x = s_vx[ib]-cx; p1y = s_vy[ib]-cy; p1z = s_vz[ib]-cz;
        p2x = s_vx[ic]-cx; p2y = s_vy[ic]-cy; p2z = s_vz[ic]-cz;
        q0x = p1y*p2z - p1z*p2y;
        q0y = p1z*p2x - p1x*p2z;
        q0z = p1x*p2y - p1y*p2x;
        float term = p0x*q0x + p0y*q0y + p0z*q0z;
        atomicAdd(&s_vol, term);
      }
      __syncthreads();
      float press = pP[0]*190.f + 10.f;
      float st    = pS[0]*0.018f + 0.002f;
      float tv    = expf(press / 2500.f);
      float vol   = s_vol / 6.f;
      float coeff = 2500.f * (vol - tv);
      if (act) {
        float q1x = p2y*p0z - p2z*p0y;
        float q1y = p2z*p0x - p2x*p0z;
        float q1z = p2x*p0y - p2y*p0x;
        float q2x = p0y*p1z - p0z*p1y;
        float q2y = p0z*p1x - p0x*p1z;
        float q2z = p0x*p1y - p0y*p1x;
        float e1x = p1x-p0x, e1y = p1y-p0y, e1z = p1z-p0z;
        float e2x = p2x-p0x, e2y = p2y-p0y, e2z = p2z-p0z;
        float nx = e1y*e2z - e1z*e2y;
        float ny = e1z*e2x - e1x*e2z;
        float nz = e1x*e2y - e1y*e2x;
        float S  = nx*nx + ny*ny + nz*nz + 1e-12f;
        float wt = st / (2.f * sqrtf(S));
        float dx = e1x-e2x, dy = e1y-e2y, dz = e1z-e2z;
        float g0x = wt*(dy*nz - dz*ny), g0y = wt*(dz*nx - dx*nz), g0z = wt*(dx*ny - dy*nx);
        float g1x = wt*(e2y*nz - e2z*ny), g1y = wt*(e2z*nx - e2x*nz), g1z = wt*(e2x*ny - e2y*nx);
        float g2x = wt*(ny*e1z - nz*e1y), g2y = wt*(nz*e1x - nx*e1z), g2z = wt*(nx*e1y - ny*e1x);
        float k = coeff / 6.f;
        atomicAdd(&s_gx[ia], g0x + k*q0x); atomicAdd(&s_gy[ia], g0y + k*q0y); atomicAdd(&s_gz[ia], g0z + k*q0z);
        atomicAdd(&s_gx[ib], g1x + k*q1x); atomicAdd(&s_gy[ib], g1y + k*q1y); atomicAdd(&s_gz[ib], g1z + k*q1z);
        atomicAdd(&s_gx[ic], g2x + k*q2x); atomicAdd(&s_gy[ic], g2y + k*q2y); atomicAdd(&s_gz[ic], g2z + k*q2z);
        atomicAdd(&s_csx, q0x+q1x+q2x);
        atomicAdd(&s_csy, q0y+q1y+q2y);
        atomicAdd(&s_csz, q0z+q1z+q2z);
      }
      __syncthreads();
      if (t < VP) {
        float corr = coeff / 384.f;   // coeff * (1/6) * (1/64) centroid chain
        s_fx[t] = -(s_gx[t] - corr*s_csx);
        s_fy[t] = -(s_gy[t] - corr*s_csy);
        s_fz[t] = -(s_gz[t] - corr*s_csz);
      }
    }
    __syncthreads();
    if (t < VP) {
      int l = s_lab[t];
      bool leader = true;
      for (int s = 0; s < t; ++s) if (s_lab[s] == l) { leader = false; break; }
      if (leader) {
        float sx = 0.f, sy = 0.f, sz = 0.f;
        for (int s = t; s < VP; ++s)
          if (s_lab[s] == l) { sx += s_fx[s]; sy += s_fy[s]; sz += s_fz[s]; }
        atomicAdd(&cs2[3*l+0], sx);
        atomicAdd(&cs2[3*l+1], sy);
        atomicAdd(&cs2[3*l+2], sz);
      }
    }
    if (t < VP) asti(&parent[c*VP + t], c*VP + t);   // reinit for next iter
    gbar(syncv, ++seq, t);   // D: force sums + parent reinit complete

    // ===== it==4: write final vertices straight to d_out ================
    if (it == 4 && t < VP) {
      int i = c*VP + t;
      int l = s_lab[t];
      float cc = fmaxf(ald(&cc1[l]), 1.f);
      out[3*i+0] = s_vx[t] + 1e-5f*(ald(&cs2[3*l+0])/cc);
      out[3*i+1] = s_vy[t] + 1e-5f*(ald(&cs2[3*l+1])/cc);
      out[3*i+2] = s_vz[t] + 1e-5f*(ald(&cs2[3*l+2])/cc);
    }
  }
}

extern "C" void kernel_launch(void* const* d_in, const int* in_sizes, int n_in,
                              void* d_out, int out_size, void* d_ws, size_t ws_size,
                              hipStream_t stream) {
  const float* inV   = (const float*)d_in[0];
  const float* bb    = (const float*)d_in[1];
  const float* pP    = (const float*)d_in[2];
  const float* pS    = (const float*)d_in[3];
  const int*   faces = (const int*)d_in[4];
  const int*   cfl   = (const int*)d_in[6];

  char* w = (char*)d_ws;
  int*   parent  = (int*)w;   w += NV*sizeof(int);          // 32 KB
  int*   labelsF = (int*)w;   w += NV*sizeof(int);          // 32 KB
  float* sumsA   = (float*)w; w += 2*NV*3*sizeof(float);    // 192 KB (2 parities)
  float* countsA = (float*)w; w += 2*NV*sizeof(float);      // 64 KB
  float* sumsB   = (float*)w; w += 2*NV*3*sizeof(float);    // 192 KB
  int*   syncv   = (int*)w;   w += 256*sizeof(int);

  hipMemsetAsync(syncv, 0, 256*sizeof(int), stream);
  soap_fused<<<NBLK, NTHR, 0, stream>>>(inV, bb, pP, pS, faces, cfl,
                                        (float*)d_out, parent, labelsF,
                                        sumsA, countsA, sumsB, syncv);
}